// Round 1
// baseline (138.102 us; speedup 1.0000x reference)
//
#include <hip/hip_runtime.h>

// DeformConv3D_alternative: B=1, C=16->16, S=32, ks=3, N=27, fp32.
// Inverse mapping of the reference's (non-block-clean) rearrange, fused
// sample + strided conv. xp = zero-padded channel-last x in ws for
// float4 corner gathers without bounds checks.

#define NCH 16
#define SS 32
#define PADDIM 34
#define PLANE 32768            // 32*32*32 (x channel stride, offset plane stride)

__device__ __forceinline__ float4 f4fma(float s, const float4 a, const float4 b) {
  return make_float4(fmaf(s, a.x, b.x), fmaf(s, a.y, b.y),
                     fmaf(s, a.z, b.z), fmaf(s, a.w, b.w));
}
__device__ __forceinline__ float4 f4scale(float s, const float4 a) {
  return make_float4(s * a.x, s * a.y, s * a.z, s * a.w);
}

// Reference semantics: q0=clip(floor(p),0,33), q1=clip(floor(p)+1,0,33);
// mask=(p<1)|(p>32) -> p=floor(p); p=clip(p,0,33); l=1+q0-p; h=1-q1+p.
__device__ __forceinline__ void axis_interp(float p, int& q0, int& q1,
                                            float& lo, float& hi) {
  float fl = floorf(p);
  int fi = (int)fl;
  q0 = min(max(fi, 0), 33);
  q1 = min(max(fi + 1, 0), 33);
  float pm = (p < 1.f || p > 32.f) ? fl : p;
  pm = fminf(fmaxf(pm, 0.f), 33.f);
  lo = 1.f + (float)q0 - pm;
  hi = 1.f - (float)q1 + pm;
}

// ---- prep: padded channel-last x: xp[qx][qy][qz][c], qx,qy,qz in [0,34)
__global__ void prep_xp(const float* __restrict__ x, float* __restrict__ xp) {
  int idx = blockIdx.x * 256 + threadIdx.x;       // [0, 34^3*16)
  if (idx >= PADDIM * PADDIM * PADDIM * NCH) return;
  int c = idx & 15;
  int site = idx >> 4;
  int qz = site % PADDIM;
  int t = site / PADDIM;
  int qy = t % PADDIM;
  int qx = t / PADDIM;
  float v = 0.f;
  if (qx >= 1 && qx <= 32 && qy >= 1 && qy <= 32 && qz >= 1 && qz <= 32)
    v = x[c * PLANE + ((qx - 1) * 32 + (qy - 1)) * 32 + (qz - 1)];
  xp[idx] = v;
}

// ---- prep: Wt[t*256 + cin*16 + o] = W[o*432 + cin*27 + t]
__global__ void prep_wt(const float* __restrict__ W, float* __restrict__ Wt) {
  int idx = blockIdx.x * 256 + threadIdx.x;
  if (idx >= 6912) return;
  int o = idx & 15;
  int r = idx >> 4;
  int cw = r & 15;
  int t = r >> 4;
  Wt[idx] = W[(o * 16 + cw) * 27 + t];
}

__device__ __forceinline__ float4 corner_direct(const float* __restrict__ x,
                                                int qx, int qy, int qz, int c0) {
  if (qx < 1 || qx > 32 || qy < 1 || qy > 32 || qz < 1 || qz > 32)
    return make_float4(0.f, 0.f, 0.f, 0.f);
  int bi = ((qx - 1) * 32 + (qy - 1)) * 32 + (qz - 1);
  const float* xb = x + c0 * PLANE + bi;
  return make_float4(xb[0], xb[PLANE], xb[2 * PLANE], xb[3 * PLANE]);
}

// Block: 256 threads = 32 k-positions x 4 channel-groups x 2 tap-halves.
// Grid: 1024 blocks = (i in [0,32)) x (j in [0,32)).
template <bool FAST>
__global__ __launch_bounds__(256) void deform_main(
    const float* __restrict__ x, const float* __restrict__ offset,
    const float* __restrict__ W, const float* __restrict__ Wt,
    const float* __restrict__ xp, float* __restrict__ out) {
  __shared__ float red[8][32][20];   // pad 16->20 floats (16B-aligned rows)

  int tid = threadIdx.x;
  int k = tid & 31;
  int c4 = (tid >> 5) & 3;
  int th = tid >> 7;                 // tap half: t = th, th+2, ...
  int i = blockIdx.x >> 5;
  int j = blockIdx.x & 31;

  float4 acc0 = make_float4(0.f, 0.f, 0.f, 0.f);
  float4 acc1 = acc0, acc2 = acc0, acc3 = acc0;

  for (int t = th; t < 27; t += 2) {
    int alpha = t / 9;
    int beta = (t / 3) % 3;
    int gamma = t % 3;
    // inverse of the reference rearrange: (i,j,k,alpha,beta,gamma)->(h',w',d',n)
    int G = 3072 * alpha + 96 * j + 3 * k + gamma;
    int wp = G / 288;
    int u = G - wp * 288;
    int dp = u / 9;
    int m = u - dp * 9;
    int n = 9 * beta + m;
    int mdiv3 = m / 3;
    int mmod3 = m - mdiv3 * 3;

    int sidx = i * 1024 + wp * 32 + dp;
    float ox = offset[n * PLANE + sidx];
    float oy = offset[(n + 27) * PLANE + sidx];
    float oz = offset[(n + 54) * PLANE + sidx];

    // p = base(1-indexed padded) + kernel offset (idx-1) + offset
    float px = (float)(i + beta) + ox;        // (i+1) + (beta-1)
    float py = (float)(wp + mdiv3) + oy;      // (wp+1) + (mdiv3-1)
    float pz = (float)(dp + mmod3) + oz;      // (dp+1) + (mmod3-1)

    int q0x, q1x, q0y, q1y, q0z, q1z;
    float lx, hx, ly, hy, lz, hz;
    axis_interp(px, q0x, q1x, lx, hx);
    axis_interp(py, q0y, q1y, ly, hy);
    axis_interp(pz, q0z, q1z, lz, hz);

    float a00 = ly * lz, a01 = ly * hz, a10 = hy * lz, a11 = hy * hz;
    float w000 = lx * a00, w001 = lx * a01, w010 = lx * a10, w011 = lx * a11;
    float w100 = hx * a00, w101 = hx * a01, w110 = hx * a10, w111 = hx * a11;

    float4 s4;
    if (FAST) {
      const float4* xp4 = (const float4*)xp;
      int b00 = (q0x * PADDIM + q0y) * PADDIM;   // (q0x,q0y)
      int b01 = (q0x * PADDIM + q1y) * PADDIM;   // (q0x,q1y)
      int b10 = (q1x * PADDIM + q0y) * PADDIM;   // (q1x,q0y)
      int b11 = (q1x * PADDIM + q1y) * PADDIM;   // (q1x,q1y)
      s4 = f4scale(w000, xp4[(b00 + q0z) * 4 + c4]);
      s4 = f4fma(w001, xp4[(b00 + q1z) * 4 + c4], s4);
      s4 = f4fma(w010, xp4[(b01 + q0z) * 4 + c4], s4);
      s4 = f4fma(w011, xp4[(b01 + q1z) * 4 + c4], s4);
      s4 = f4fma(w100, xp4[(b10 + q0z) * 4 + c4], s4);
      s4 = f4fma(w101, xp4[(b10 + q1z) * 4 + c4], s4);
      s4 = f4fma(w110, xp4[(b11 + q0z) * 4 + c4], s4);
      s4 = f4fma(w111, xp4[(b11 + q1z) * 4 + c4], s4);
    } else {
      int c0 = c4 * 4;
      s4 = f4scale(w000, corner_direct(x, q0x, q0y, q0z, c0));
      s4 = f4fma(w001, corner_direct(x, q0x, q0y, q1z, c0), s4);
      s4 = f4fma(w010, corner_direct(x, q0x, q1y, q0z, c0), s4);
      s4 = f4fma(w011, corner_direct(x, q0x, q1y, q1z, c0), s4);
      s4 = f4fma(w100, corner_direct(x, q1x, q0y, q0z, c0), s4);
      s4 = f4fma(w101, corner_direct(x, q1x, q0y, q1z, c0), s4);
      s4 = f4fma(w110, corner_direct(x, q1x, q1y, q0z, c0), s4);
      s4 = f4fma(w111, corner_direct(x, q1x, q1y, q1z, c0), s4);
    }

    // acc[o] += W[o, cin, t] * s(cin), cin = c4*4 + cc
    float sarr[4] = {s4.x, s4.y, s4.z, s4.w};
    if (FAST) {
      const float4* Wt4 = (const float4*)Wt;
      int wb = t * 64 + c4 * 16;       // float4 index: t*256/4 + (c4*4)*16/4
#pragma unroll
      for (int cc = 0; cc < 4; cc++) {
        float s = sarr[cc];
        acc0 = f4fma(s, Wt4[wb + cc * 4 + 0], acc0);
        acc1 = f4fma(s, Wt4[wb + cc * 4 + 1], acc1);
        acc2 = f4fma(s, Wt4[wb + cc * 4 + 2], acc2);
        acc3 = f4fma(s, Wt4[wb + cc * 4 + 3], acc3);
      }
    } else {
#pragma unroll
      for (int cc = 0; cc < 4; cc++) {
        float s = sarr[cc];
        const float* wr = W + (c4 * 4 + cc) * 27 + t;  // + o*432
        acc0.x = fmaf(s, wr[0 * 432], acc0.x);
        acc0.y = fmaf(s, wr[1 * 432], acc0.y);
        acc0.z = fmaf(s, wr[2 * 432], acc0.z);
        acc0.w = fmaf(s, wr[3 * 432], acc0.w);
        acc1.x = fmaf(s, wr[4 * 432], acc1.x);
        acc1.y = fmaf(s, wr[5 * 432], acc1.y);
        acc1.z = fmaf(s, wr[6 * 432], acc1.z);
        acc1.w = fmaf(s, wr[7 * 432], acc1.w);
        acc2.x = fmaf(s, wr[8 * 432], acc2.x);
        acc2.y = fmaf(s, wr[9 * 432], acc2.y);
        acc2.z = fmaf(s, wr[10 * 432], acc2.z);
        acc2.w = fmaf(s, wr[11 * 432], acc2.w);
        acc3.x = fmaf(s, wr[12 * 432], acc3.x);
        acc3.y = fmaf(s, wr[13 * 432], acc3.y);
        acc3.z = fmaf(s, wr[14 * 432], acc3.z);
        acc3.w = fmaf(s, wr[15 * 432], acc3.w);
      }
    }
  }

  // 8-way reduction over (tap-half, c4) groups via LDS
  int grp = th * 4 + c4;
  float* r = &red[grp][k][0];
  ((float4*)r)[0] = acc0;
  ((float4*)r)[1] = acc1;
  ((float4*)r)[2] = acc2;
  ((float4*)r)[3] = acc3;
  __syncthreads();

#pragma unroll
  for (int rep = 0; rep < 2; rep++) {
    int idx = tid + rep * 256;       // [0,512): o*32 + k
    int o = idx >> 5;
    int kk = idx & 31;
    float v = 0.f;
#pragma unroll
    for (int g = 0; g < 8; g++) v += red[g][kk][o];
    out[((o * 32 + i) * 32 + j) * 32 + kk] = v;
  }
}

extern "C" void kernel_launch(void* const* d_in, const int* in_sizes, int n_in,
                              void* d_out, int out_size, void* d_ws, size_t ws_size,
                              hipStream_t stream) {
  const float* x = (const float*)d_in[0];      // 16*32^3
  const float* off = (const float*)d_in[1];    // 81*32^3
  const float* W = (const float*)d_in[2];      // 16*16*27
  float* out = (float*)d_out;

  const size_t WT_BYTES = 6912 * sizeof(float);                       // 27,648
  const size_t XP_BYTES = (size_t)PADDIM * PADDIM * PADDIM * NCH * 4; // 2,515,456

  if (ws_size >= WT_BYTES + XP_BYTES) {
    float* wt = (float*)d_ws;
    float* xp = wt + 6912;           // byte offset 27648, 16B-aligned
    prep_wt<<<27, 256, 0, stream>>>(W, wt);
    prep_xp<<<(PADDIM * PADDIM * PADDIM * NCH + 255) / 256, 256, 0, stream>>>(x, xp);
    deform_main<true><<<1024, 256, 0, stream>>>(x, off, W, wt, xp, out);
  } else {
    deform_main<false><<<1024, 256, 0, stream>>>(x, off, W, nullptr, nullptr, out);
  }
}